// Round 1
// baseline (1262.250 us; speedup 1.0000x reference)
//
#include <hip/hip_runtime.h>

// GNN1: 3x GraphConv(add) + linear head on MI355X.
// Pipeline: CSR-by-dst build -> gather-sum aggregation (bf16, f32 acc)
//           -> fused concat-K bf16 MFMA GEMM (agg@W_rel + h@W_root) + bias + ReLU.
// Workspace: ~164 MB.

typedef unsigned short u16;
typedef unsigned int u32;

#define NN 50000
#define NE 1600000
#define MPAD 50176                 // 392*128, padded row count for GEMM A staging
#define GRID_M ((NN + 127) / 128)  // 391

using frag8 = __attribute__((ext_vector_type(8))) short;  // 8 bf16 (4 VGPRs)
using f32x4 = __attribute__((ext_vector_type(4))) float;

__device__ __forceinline__ u16 f2bf(float f) {  // RNE f32->bf16
  u32 u = __float_as_uint(f);
  u32 r = u + 0x7fffu + ((u >> 16) & 1u);
  return (u16)(r >> 16);
}
__device__ __forceinline__ float lo2f(u32 u) { return __uint_as_float(u << 16); }
__device__ __forceinline__ float hi2f(u32 u) { return __uint_as_float(u & 0xffff0000u); }
__device__ __forceinline__ u32 pack2(float a, float b) {
  return (u32)f2bf(a) | ((u32)f2bf(b) << 16);
}

__device__ __forceinline__ void g2l16(const void* g, void* l) {
  // async global->LDS, 16B per lane; LDS dest must be wave-uniform base + lane*16
  __builtin_amdgcn_global_load_lds((const __attribute__((address_space(1))) void*)g,
                                   (__attribute__((address_space(3))) void*)l, 16, 0, 0);
}

// ---------------- CSR build ----------------

__global__ void zero_i32(int* p, int n) {
  int i = blockIdx.x * 256 + threadIdx.x;
  if (i < n) p[i] = 0;
}

__global__ void hist_k(const int* __restrict__ dst, int* __restrict__ deg, int ne) {
  int i = blockIdx.x * 256 + threadIdx.x;
  if (i < ne) atomicAdd(&deg[dst[i]], 1);
}

// single-block exclusive scan of 50000 ints (49 chunks of 1024, Hillis-Steele)
__global__ void scan_k(const int* __restrict__ deg, int* __restrict__ rs,
                       int* __restrict__ cur, int n) {
  __shared__ int buf[1024];
  const int tid = threadIdx.x;
  int carry = 0;
  for (int base = 0; base < n; base += 1024) {
    int i = base + tid;
    int v = (i < n) ? deg[i] : 0;
    buf[tid] = v;
    __syncthreads();
    for (int off = 1; off < 1024; off <<= 1) {
      int t = (tid >= off) ? buf[tid - off] : 0;
      __syncthreads();
      buf[tid] += t;
      __syncthreads();
    }
    int excl = carry + buf[tid] - v;
    if (i < n) { rs[i] = excl; cur[i] = excl; }
    carry += buf[1023];
    __syncthreads();  // protect buf before next chunk writes
  }
  if (tid == 0) rs[n] = carry;
}

__global__ void fill_k(const int* __restrict__ src, const int* __restrict__ dst,
                       int* __restrict__ cur, int* __restrict__ csr, int ne) {
  int i = blockIdx.x * 256 + threadIdx.x;
  if (i < ne) {
    int p = atomicAdd(&cur[dst[i]], 1);
    csr[p] = src[i];
  }
}

// ---------------- dtype conversion ----------------

__global__ void f2bf_vec(const float4* __restrict__ in, uint2* __restrict__ out, int n4) {
  int i = blockIdx.x * 256 + threadIdx.x;
  if (i < n4) {
    float4 v = in[i];
    uint2 o;
    o.x = pack2(v.x, v.y);
    o.y = pack2(v.z, v.w);
    out[i] = o;
  }
}

// out[n][k] (k-contiguous, [N][Ka+Kb]) = bf16( k<Ka ? Wa[k][n] : Wb[k-Ka][n] )
__global__ void wtrans(const float* __restrict__ Wa, int Ka, const float* __restrict__ Wb,
                       int Kb, int N, u16* __restrict__ out) {
  int idx = blockIdx.x * 256 + threadIdx.x;
  int Kt = Ka + Kb;
  if (idx >= N * Kt) return;
  int n = idx / Kt;
  int k = idx - n * Kt;
  float v = (k < Ka) ? Wa[(size_t)k * N + n] : Wb[(size_t)(k - Ka) * N + n];
  out[idx] = f2bf(v);
}

// ---------------- aggregation: one wave per node, gather-sum ----------------
// EPL = u16 elements per lane: 8 (512-dim rows, 16B/lane) or 2 (128-dim, 4B/lane)

__device__ __forceinline__ void acc8(float* a, uint4 v) {
  a[0] += lo2f(v.x); a[1] += hi2f(v.x);
  a[2] += lo2f(v.y); a[3] += hi2f(v.y);
  a[4] += lo2f(v.z); a[5] += hi2f(v.z);
  a[6] += lo2f(v.w); a[7] += hi2f(v.w);
}

template <int EPL>
__global__ __launch_bounds__(256) void agg_gather(const u16* __restrict__ H, int ldh,
                                                  u16* __restrict__ Out, int ldo,
                                                  const int* __restrict__ rs,
                                                  const int* __restrict__ csr, int n) {
  int w = (blockIdx.x * 256 + threadIdx.x) >> 6;
  int lane = threadIdx.x & 63;
  if (w >= n) return;
  int beg = rs[w], end = rs[w + 1];
  float acc[EPL];
#pragma unroll
  for (int i = 0; i < EPL; ++i) acc[i] = 0.f;
  int e = beg;
  const size_t lo = (size_t)lane * EPL;
  if constexpr (EPL == 8) {
    for (; e + 4 <= end; e += 4) {  // unroll-4 for memory-level parallelism
      int s0 = csr[e], s1 = csr[e + 1], s2 = csr[e + 2], s3 = csr[e + 3];
      uint4 v0 = *(const uint4*)(H + (size_t)s0 * ldh + lo);
      uint4 v1 = *(const uint4*)(H + (size_t)s1 * ldh + lo);
      uint4 v2 = *(const uint4*)(H + (size_t)s2 * ldh + lo);
      uint4 v3 = *(const uint4*)(H + (size_t)s3 * ldh + lo);
      acc8(acc, v0); acc8(acc, v1); acc8(acc, v2); acc8(acc, v3);
    }
    for (; e < end; ++e) {
      uint4 v = *(const uint4*)(H + (size_t)csr[e] * ldh + lo);
      acc8(acc, v);
    }
    uint4 o;
    o.x = pack2(acc[0], acc[1]); o.y = pack2(acc[2], acc[3]);
    o.z = pack2(acc[4], acc[5]); o.w = pack2(acc[6], acc[7]);
    *(uint4*)(Out + (size_t)w * ldo + lo) = o;
  } else {
    for (; e + 4 <= end; e += 4) {
      int s0 = csr[e], s1 = csr[e + 1], s2 = csr[e + 2], s3 = csr[e + 3];
      u32 v0 = *(const u32*)(H + (size_t)s0 * ldh + lo);
      u32 v1 = *(const u32*)(H + (size_t)s1 * ldh + lo);
      u32 v2 = *(const u32*)(H + (size_t)s2 * ldh + lo);
      u32 v3 = *(const u32*)(H + (size_t)s3 * ldh + lo);
      acc[0] += lo2f(v0); acc[1] += hi2f(v0);
      acc[0] += lo2f(v1); acc[1] += hi2f(v1);
      acc[0] += lo2f(v2); acc[1] += hi2f(v2);
      acc[0] += lo2f(v3); acc[1] += hi2f(v3);
    }
    for (; e < end; ++e) {
      u32 v = *(const u32*)(H + (size_t)csr[e] * ldh + lo);
      acc[0] += lo2f(v); acc[1] += hi2f(v);
    }
    *(u32*)(Out + (size_t)w * ldo + lo) = pack2(acc[0], acc[1]);
  }
}

// ---------------- GEMM: C = [A1|A2] @ Bt^T + bias (+ReLU), bf16 MFMA ----------------
// A1: [MPAD][lda1] bf16 covers virtual k in [0,K1); A2 covers [K1,Ktot).
// Bt: [N][Ktot] bf16 (k-contiguous). 128xBN block tile, BK=32, 4 waves 2x2,
// wave tile 64 x BN/2 -> 4 x NT tiles of v_mfma_f32_16x16x32_bf16.

template <int BN>
__global__ __launch_bounds__(256) void gemm_mfma(
    const u16* __restrict__ A1, int lda1, const u16* __restrict__ A2, int lda2, int K1,
    int Ktot, const u16* __restrict__ Bt, const float* __restrict__ bias, int relu,
    u16* __restrict__ out_bf, int ldob, float* __restrict__ out_f32, int ldof, int M) {
  constexpr int NT = BN / 32;
  __shared__ u16 lA[128 * 32];
  __shared__ u16 lB[BN * 32];
  const int tid = threadIdx.x;
  const int lane = tid & 63;
  const int wv = tid >> 6;
  const int wm = (wv >> 1) * 64;        // wave m-offset in block tile
  const int wn = (wv & 1) * (BN / 2);   // wave n-offset
  const int m0 = blockIdx.x * 128;
  const int n0 = blockIdx.y * BN;
  const int r15 = lane & 15;
  const int quad = lane >> 4;

  f32x4 acc[4][NT];
#pragma unroll
  for (int i = 0; i < 4; ++i)
#pragma unroll
    for (int j = 0; j < NT; ++j) acc[i][j] = (f32x4){0.f, 0.f, 0.f, 0.f};

  for (int kk = 0; kk < Ktot; kk += 32) {
    const u16* Ab;
    int lda;
    if (kk < K1) { Ab = A1 + kk; lda = lda1; }
    else         { Ab = A2 + (kk - K1); lda = lda2; }
#pragma unroll
    for (int i = 0; i < 2; ++i) {  // A tile: 128 rows x 32 k = 8KB
      int li = tid + i * 256;
      int row = li >> 2;
      int kc = (li & 3) * 8;
      g2l16(Ab + (size_t)(m0 + row) * lda + kc, &lA[li * 8]);
    }
#pragma unroll
    for (int i = 0; i < BN / 64; ++i) {  // B tile: BN n-rows x 32 k
      int li = tid + i * 256;
      int nrow = li >> 2;
      int kc = (li & 3) * 8;
      g2l16(Bt + (size_t)(n0 + nrow) * Ktot + (kk + kc), &lB[li * 8]);
    }
    __syncthreads();
    frag8 af[4], bfr[NT];
#pragma unroll
    for (int mt = 0; mt < 4; ++mt)
      af[mt] = *(const frag8*)&lA[(wm + mt * 16 + r15) * 32 + quad * 8];
#pragma unroll
    for (int nt = 0; nt < NT; ++nt)
      bfr[nt] = *(const frag8*)&lB[(wn + nt * 16 + r15) * 32 + quad * 8];
#pragma unroll
    for (int mt = 0; mt < 4; ++mt)
#pragma unroll
      for (int nt = 0; nt < NT; ++nt)
        acc[mt][nt] =
            __builtin_amdgcn_mfma_f32_16x16x32_bf16(af[mt], bfr[nt], acc[mt][nt], 0, 0, 0);
    __syncthreads();
  }

  // epilogue: C/D layout col=lane&15, row=quad*4+reg
#pragma unroll
  for (int mt = 0; mt < 4; ++mt) {
    int rbase = m0 + wm + mt * 16 + quad * 4;
#pragma unroll
    for (int r = 0; r < 4; ++r) {
      int row = rbase + r;
      if (row < M) {
#pragma unroll
        for (int nt = 0; nt < NT; ++nt) {
          int c = n0 + wn + nt * 16 + r15;
          float v = acc[mt][nt][r] + bias[c];
          if (relu) v = fmaxf(v, 0.f);
          if (out_f32) out_f32[(size_t)row * ldof + c] = v;
          if (out_bf) out_bf[(size_t)row * ldob + c] = f2bf(v);
        }
      }
    }
  }
}

// ---------------- launch ----------------

extern "C" void kernel_launch(void* const* d_in, const int* in_sizes, int n_in, void* d_out,
                              int out_size, void* d_ws, size_t ws_size, hipStream_t stream) {
  const float* x = (const float*)d_in[0];
  const float* W1r = (const float*)d_in[1];
  const float* b1 = (const float*)d_in[2];
  const float* W1o = (const float*)d_in[3];
  const float* W2r = (const float*)d_in[4];
  const float* b2 = (const float*)d_in[5];
  const float* W2o = (const float*)d_in[6];
  const float* W3r = (const float*)d_in[7];
  const float* b3 = (const float*)d_in[8];
  const float* W3o = (const float*)d_in[9];
  const float* Wl = (const float*)d_in[10];
  const float* bl = (const float*)d_in[11];
  const int* src = (const int*)d_in[12];
  const int* dst = src + NE;

  size_t off = 0;
  char* ws = (char*)d_ws;
  auto take = [&](size_t bytes) -> void* {
    void* p = ws + off;
    off = (off + bytes + 255) & ~(size_t)255;
    return p;
  };
  u16* h13 = (u16*)take((size_t)MPAD * 512 * 2);   // h1, later h3
  u16* h2 = (u16*)take((size_t)MPAD * 512 * 2);    // h2
  char* Rg = (char*)take((size_t)MPAD * 512 * 2);  // phase1: hx|agg128, phase2/3: agg512
  u16* hx = (u16*)Rg;
  u16* agg128 = (u16*)(Rg + (size_t)MPAD * 128 * 2);
  u16* agg512 = (u16*)Rg;
  u16* wt1 = (u16*)take((size_t)512 * 256 * 2);
  u16* wt2 = (u16*)take((size_t)512 * 1024 * 2);
  u16* wt3 = (u16*)take((size_t)512 * 1024 * 2);
  u16* wtl = (u16*)take((size_t)64 * 512 * 2);
  int* deg = (int*)take((size_t)NN * 4);
  int* rs = (int*)take((size_t)(NN + 1) * 4);
  int* cur = (int*)take((size_t)NN * 4);
  int* csr = (int*)take((size_t)NE * 4);

  float* out_logits = (float*)d_out;
  float* out_embed = out_logits + (size_t)NN * 64;

  // CSR by dst
  zero_i32<<<(NN + 255) / 256, 256, 0, stream>>>(deg, NN);
  hist_k<<<(NE + 255) / 256, 256, 0, stream>>>(dst, deg, NE);
  scan_k<<<1, 1024, 0, stream>>>(deg, rs, cur, NN);
  fill_k<<<(NE + 255) / 256, 256, 0, stream>>>(src, dst, cur, csr, NE);

  // conversions
  f2bf_vec<<<(NN * 128 / 4 + 255) / 256, 256, 0, stream>>>((const float4*)x, (uint2*)hx,
                                                           NN * 128 / 4);
  wtrans<<<(512 * 256 + 255) / 256, 256, 0, stream>>>(W1r, 128, W1o, 128, 512, wt1);
  wtrans<<<(512 * 1024 + 255) / 256, 256, 0, stream>>>(W2r, 512, W2o, 512, 512, wt2);
  wtrans<<<(512 * 1024 + 255) / 256, 256, 0, stream>>>(W3r, 512, W3o, 512, 512, wt3);
  wtrans<<<(64 * 512 + 255) / 256, 256, 0, stream>>>(Wl, 512, Wl, 0, 64, wtl);

  // layer 1: agg(x) ; h1 = relu([agg|x] @ [W1r;W1o] + b1)
  agg_gather<2><<<(NN + 3) / 4, 256, 0, stream>>>(hx, 128, agg128, 128, rs, csr, NN);
  gemm_mfma<128><<<dim3(GRID_M, 4), 256, 0, stream>>>(agg128, 128, hx, 128, 128, 256, wt1,
                                                      b1, 1, h13, 512, (float*)nullptr, 0, NN);
  // layer 2
  agg_gather<8><<<(NN + 3) / 4, 256, 0, stream>>>(h13, 512, agg512, 512, rs, csr, NN);
  gemm_mfma<128><<<dim3(GRID_M, 4), 256, 0, stream>>>(agg512, 512, h13, 512, 512, 1024, wt2,
                                                      b2, 1, h2, 512, (float*)nullptr, 0, NN);
  // layer 3 (h3 -> h13 bf16 + d_out f32 embed)
  agg_gather<8><<<(NN + 3) / 4, 256, 0, stream>>>(h2, 512, agg512, 512, rs, csr, NN);
  gemm_mfma<128><<<dim3(GRID_M, 4), 256, 0, stream>>>(agg512, 512, h2, 512, 512, 1024, wt3,
                                                      b3, 1, h13, 512, out_embed, 512, NN);
  // head: logits = h3 @ W_lin + b_lin
  gemm_mfma<64><<<dim3(GRID_M, 1), 256, 0, stream>>>(h13, 512, h13, 512, 512, 512, wtl, bl,
                                                     0, (u16*)nullptr, 0, out_logits, 64, NN);
}

// Round 2
// 1162.395 us; speedup vs baseline: 1.0859x; 1.0859x over previous
//
#include <hip/hip_runtime.h>

// GNN1: 3x GraphConv(add) + linear head on MI355X.
// R2: band-grouped CSR (src-locality for L2), unroll-8 gather, multi-block scan.

typedef unsigned short u16;
typedef unsigned int u32;

#define NN 50000
#define NE 1600000
#define MPAD 50176
#define GRID_M ((NN + 127) / 128)  // 391
#define NB 25                      // src bands: band = src >> 11 (2048 rows = 2MB h-slice)
#define BSH 11

using frag8 = __attribute__((ext_vector_type(8))) short;
using f32x4 = __attribute__((ext_vector_type(4))) float;

__device__ __forceinline__ u16 f2bf(float f) {
  u32 u = __float_as_uint(f);
  u32 r = u + 0x7fffu + ((u >> 16) & 1u);
  return (u16)(r >> 16);
}
__device__ __forceinline__ float lo2f(u32 u) { return __uint_as_float(u << 16); }
__device__ __forceinline__ float hi2f(u32 u) { return __uint_as_float(u & 0xffff0000u); }
__device__ __forceinline__ u32 pack2(float a, float b) {
  return (u32)f2bf(a) | ((u32)f2bf(b) << 16);
}

__device__ __forceinline__ void g2l16(const void* g, void* l) {
  __builtin_amdgcn_global_load_lds((const __attribute__((address_space(1))) void*)g,
                                   (__attribute__((address_space(3))) void*)l, 16, 0, 0);
}

// ---------------- CSR build (band-grouped) ----------------

__global__ void zero_i32(int* p, int n) {
  int i = blockIdx.x * 256 + threadIdx.x;
  if (i < n) p[i] = 0;
}

// count per (dst, band)
__global__ void hist2_k(const int* __restrict__ src, const int* __restrict__ dst,
                        int* __restrict__ cnt2, int ne) {
  int i = blockIdx.x * 256 + threadIdx.x;
  if (i < ne) atomicAdd(&cnt2[dst[i] * NB + (src[i] >> BSH)], 1);
}

__global__ void deg_k(const int* __restrict__ cnt2, int* __restrict__ deg, int n) {
  int i = blockIdx.x * 256 + threadIdx.x;
  if (i < n) {
    int s = 0;
#pragma unroll
    for (int b = 0; b < NB; ++b) s += cnt2[i * NB + b];
    deg[i] = s;
  }
}

// multi-block exclusive scan: scan1 (per-1024-chunk) -> scan2 (block sums) -> scan3 (add)
__global__ void scan1_k(const int* __restrict__ deg, int* __restrict__ rs,
                        int* __restrict__ bsum, int n) {
  __shared__ int sh[256];
  const int t = threadIdx.x;
  const int i0 = blockIdx.x * 1024 + t * 4;
  int v[4];
#pragma unroll
  for (int j = 0; j < 4; ++j) v[j] = (i0 + j < n) ? deg[i0 + j] : 0;
  int s = v[0] + v[1] + v[2] + v[3];
  sh[t] = s;
  __syncthreads();
  for (int off = 1; off < 256; off <<= 1) {
    int tmp = (t >= off) ? sh[t - off] : 0;
    __syncthreads();
    sh[t] += tmp;
    __syncthreads();
  }
  int run = sh[t] - s;  // exclusive
#pragma unroll
  for (int j = 0; j < 4; ++j) {
    if (i0 + j < n) rs[i0 + j] = run;
    run += v[j];
  }
  if (t == 255) bsum[blockIdx.x] = sh[255];
}

__global__ void scan2_k(int* __restrict__ bsum, int* __restrict__ bex, int nb) {
  __shared__ int sh[64];
  const int t = threadIdx.x;
  int v = (t < nb) ? bsum[t] : 0;
  sh[t] = v;
  __syncthreads();
  for (int off = 1; off < 64; off <<= 1) {
    int tmp = (t >= off) ? sh[t - off] : 0;
    __syncthreads();
    sh[t] += tmp;
    __syncthreads();
  }
  bex[t] = sh[t] - v;
}

__global__ void scan3_k(int* __restrict__ rs, const int* __restrict__ bex, int n) {
  const int i0 = blockIdx.x * 1024 + threadIdx.x * 4;
  const int add = bex[blockIdx.x];
#pragma unroll
  for (int j = 0; j < 4; ++j)
    if (i0 + j < n) rs[i0 + j] += add;
  if (blockIdx.x == 0 && threadIdx.x == 0) rs[n] = NE;
}

// per-node running offsets for each band
__global__ void band_off_k(const int* __restrict__ rs, const int* __restrict__ cnt2,
                           int* __restrict__ cur2, int n) {
  int i = blockIdx.x * 256 + threadIdx.x;
  if (i < n) {
    int run = rs[i];
#pragma unroll
    for (int b = 0; b < NB; ++b) {
      cur2[i * NB + b] = run;
      run += cnt2[i * NB + b];
    }
  }
}

__global__ void fill2_k(const int* __restrict__ src, const int* __restrict__ dst,
                        int* __restrict__ cur2, int* __restrict__ csr, int ne) {
  int i = blockIdx.x * 256 + threadIdx.x;
  if (i < ne) {
    int s = src[i];
    int p = atomicAdd(&cur2[dst[i] * NB + (s >> BSH)], 1);
    csr[p] = s;
  }
}

// ---------------- dtype conversion ----------------

__global__ void f2bf_vec(const float4* __restrict__ in, uint2* __restrict__ out, int n4) {
  int i = blockIdx.x * 256 + threadIdx.x;
  if (i < n4) {
    float4 v = in[i];
    uint2 o;
    o.x = pack2(v.x, v.y);
    o.y = pack2(v.z, v.w);
    out[i] = o;
  }
}

__global__ void wtrans(const float* __restrict__ Wa, int Ka, const float* __restrict__ Wb,
                       int Kb, int N, u16* __restrict__ out) {
  int idx = blockIdx.x * 256 + threadIdx.x;
  int Kt = Ka + Kb;
  if (idx >= N * Kt) return;
  int n = idx / Kt;
  int k = idx - n * Kt;
  float v = (k < Ka) ? Wa[(size_t)k * N + n] : Wb[(size_t)(k - Ka) * N + n];
  out[idx] = f2bf(v);
}

// ---------------- aggregation: one wave per node, gather-sum, unroll-8 ----------------

__device__ __forceinline__ void acc8(float* a, uint4 v) {
  a[0] += lo2f(v.x); a[1] += hi2f(v.x);
  a[2] += lo2f(v.y); a[3] += hi2f(v.y);
  a[4] += lo2f(v.z); a[5] += hi2f(v.z);
  a[6] += lo2f(v.w); a[7] += hi2f(v.w);
}

template <int EPL>
__global__ __launch_bounds__(256) void agg_gather(const u16* __restrict__ H, int ldh,
                                                  u16* __restrict__ Out, int ldo,
                                                  const int* __restrict__ rs,
                                                  const int* __restrict__ csr, int n) {
  int w = (blockIdx.x * 256 + threadIdx.x) >> 6;
  int lane = threadIdx.x & 63;
  if (w >= n) return;
  int beg = rs[w], end = rs[w + 1];
  float acc[EPL];
#pragma unroll
  for (int i = 0; i < EPL; ++i) acc[i] = 0.f;
  int e = beg;
  const size_t lo = (size_t)lane * EPL;
  if constexpr (EPL == 8) {
    for (; e + 8 <= end; e += 8) {
      int s[8];
#pragma unroll
      for (int j = 0; j < 8; ++j) s[j] = csr[e + j];
      uint4 v[8];
#pragma unroll
      for (int j = 0; j < 8; ++j) v[j] = *(const uint4*)(H + (size_t)s[j] * ldh + lo);
#pragma unroll
      for (int j = 0; j < 8; ++j) acc8(acc, v[j]);
    }
    for (; e < end; ++e) {
      uint4 v = *(const uint4*)(H + (size_t)csr[e] * ldh + lo);
      acc8(acc, v);
    }
    uint4 o;
    o.x = pack2(acc[0], acc[1]); o.y = pack2(acc[2], acc[3]);
    o.z = pack2(acc[4], acc[5]); o.w = pack2(acc[6], acc[7]);
    *(uint4*)(Out + (size_t)w * ldo + lo) = o;
  } else {
    for (; e + 8 <= end; e += 8) {
      int s[8];
#pragma unroll
      for (int j = 0; j < 8; ++j) s[j] = csr[e + j];
      u32 v[8];
#pragma unroll
      for (int j = 0; j < 8; ++j) v[j] = *(const u32*)(H + (size_t)s[j] * ldh + lo);
#pragma unroll
      for (int j = 0; j < 8; ++j) { acc[0] += lo2f(v[j]); acc[1] += hi2f(v[j]); }
    }
    for (; e < end; ++e) {
      u32 v = *(const u32*)(H + (size_t)csr[e] * ldh + lo);
      acc[0] += lo2f(v); acc[1] += hi2f(v);
    }
    *(u32*)(Out + (size_t)w * ldo + lo) = pack2(acc[0], acc[1]);
  }
}

// ---------------- GEMM: C = [A1|A2] @ Bt^T + bias (+ReLU), bf16 MFMA ----------------

template <int BN>
__global__ __launch_bounds__(256) void gemm_mfma(
    const u16* __restrict__ A1, int lda1, const u16* __restrict__ A2, int lda2, int K1,
    int Ktot, const u16* __restrict__ Bt, const float* __restrict__ bias, int relu,
    u16* __restrict__ out_bf, int ldob, float* __restrict__ out_f32, int ldof, int M) {
  constexpr int NT = BN / 32;
  __shared__ u16 lA[128 * 32];
  __shared__ u16 lB[BN * 32];
  const int tid = threadIdx.x;
  const int lane = tid & 63;
  const int wv = tid >> 6;
  const int wm = (wv >> 1) * 64;
  const int wn = (wv & 1) * (BN / 2);
  const int m0 = blockIdx.x * 128;
  const int n0 = blockIdx.y * BN;
  const int r15 = lane & 15;
  const int quad = lane >> 4;

  f32x4 acc[4][NT];
#pragma unroll
  for (int i = 0; i < 4; ++i)
#pragma unroll
    for (int j = 0; j < NT; ++j) acc[i][j] = (f32x4){0.f, 0.f, 0.f, 0.f};

  for (int kk = 0; kk < Ktot; kk += 32) {
    const u16* Ab;
    int lda;
    if (kk < K1) { Ab = A1 + kk; lda = lda1; }
    else         { Ab = A2 + (kk - K1); lda = lda2; }
#pragma unroll
    for (int i = 0; i < 2; ++i) {
      int li = tid + i * 256;
      int row = li >> 2;
      int kc = (li & 3) * 8;
      g2l16(Ab + (size_t)(m0 + row) * lda + kc, &lA[li * 8]);
    }
#pragma unroll
    for (int i = 0; i < BN / 64; ++i) {
      int li = tid + i * 256;
      int nrow = li >> 2;
      int kc = (li & 3) * 8;
      g2l16(Bt + (size_t)(n0 + nrow) * Ktot + (kk + kc), &lB[li * 8]);
    }
    __syncthreads();
    frag8 af[4], bfr[NT];
#pragma unroll
    for (int mt = 0; mt < 4; ++mt)
      af[mt] = *(const frag8*)&lA[(wm + mt * 16 + r15) * 32 + quad * 8];
#pragma unroll
    for (int nt = 0; nt < NT; ++nt)
      bfr[nt] = *(const frag8*)&lB[(wn + nt * 16 + r15) * 32 + quad * 8];
#pragma unroll
    for (int mt = 0; mt < 4; ++mt)
#pragma unroll
      for (int nt = 0; nt < NT; ++nt)
        acc[mt][nt] =
            __builtin_amdgcn_mfma_f32_16x16x32_bf16(af[mt], bfr[nt], acc[mt][nt], 0, 0, 0);
    __syncthreads();
  }

#pragma unroll
  for (int mt = 0; mt < 4; ++mt) {
    int rbase = m0 + wm + mt * 16 + quad * 4;
#pragma unroll
    for (int r = 0; r < 4; ++r) {
      int row = rbase + r;
      if (row < M) {
#pragma unroll
        for (int nt = 0; nt < NT; ++nt) {
          int c = n0 + wn + nt * 16 + r15;
          float v = acc[mt][nt][r] + bias[c];
          if (relu) v = fmaxf(v, 0.f);
          if (out_f32) out_f32[(size_t)row * ldof + c] = v;
          if (out_bf) out_bf[(size_t)row * ldob + c] = f2bf(v);
        }
      }
    }
  }
}

// ---------------- launch ----------------

extern "C" void kernel_launch(void* const* d_in, const int* in_sizes, int n_in, void* d_out,
                              int out_size, void* d_ws, size_t ws_size, hipStream_t stream) {
  const float* x = (const float*)d_in[0];
  const float* W1r = (const float*)d_in[1];
  const float* b1 = (const float*)d_in[2];
  const float* W1o = (const float*)d_in[3];
  const float* W2r = (const float*)d_in[4];
  const float* b2 = (const float*)d_in[5];
  const float* W2o = (const float*)d_in[6];
  const float* W3r = (const float*)d_in[7];
  const float* b3 = (const float*)d_in[8];
  const float* W3o = (const float*)d_in[9];
  const float* Wl = (const float*)d_in[10];
  const float* bl = (const float*)d_in[11];
  const int* src = (const int*)d_in[12];
  const int* dst = src + NE;

  size_t off = 0;
  char* ws = (char*)d_ws;
  auto take = [&](size_t bytes) -> void* {
    void* p = ws + off;
    off = (off + bytes + 255) & ~(size_t)255;
    return p;
  };
  u16* h13 = (u16*)take((size_t)MPAD * 512 * 2);
  u16* h2 = (u16*)take((size_t)MPAD * 512 * 2);
  char* Rg = (char*)take((size_t)MPAD * 512 * 2);
  u16* hx = (u16*)Rg;
  u16* agg128 = (u16*)(Rg + (size_t)MPAD * 128 * 2);
  u16* agg512 = (u16*)Rg;
  u16* wt1 = (u16*)take((size_t)512 * 256 * 2);
  u16* wt2 = (u16*)take((size_t)512 * 1024 * 2);
  u16* wt3 = (u16*)take((size_t)512 * 1024 * 2);
  u16* wtl = (u16*)take((size_t)64 * 512 * 2);
  int* cnt2 = (int*)take((size_t)NN * NB * 4);
  int* cur2 = (int*)take((size_t)NN * NB * 4);
  int* deg = (int*)take((size_t)NN * 4);
  int* rs = (int*)take((size_t)(NN + 1) * 4);
  int* bsum = (int*)take(64 * 4);
  int* bex = (int*)take(64 * 4);
  int* csr = (int*)take((size_t)NE * 4);

  float* out_logits = (float*)d_out;
  float* out_embed = out_logits + (size_t)NN * 64;

  const int NBLK = (NN + 1023) / 1024;  // 49

  // band-grouped CSR by dst
  zero_i32<<<(NN * NB + 255) / 256, 256, 0, stream>>>(cnt2, NN * NB);
  hist2_k<<<(NE + 255) / 256, 256, 0, stream>>>(src, dst, cnt2, NE);
  deg_k<<<(NN + 255) / 256, 256, 0, stream>>>(cnt2, deg, NN);
  scan1_k<<<NBLK, 256, 0, stream>>>(deg, rs, bsum, NN);
  scan2_k<<<1, 64, 0, stream>>>(bsum, bex, NBLK);
  scan3_k<<<NBLK, 256, 0, stream>>>(rs, bex, NN);
  band_off_k<<<(NN + 255) / 256, 256, 0, stream>>>(rs, cnt2, cur2, NN);
  fill2_k<<<(NE + 255) / 256, 256, 0, stream>>>(src, dst, cur2, csr, NE);

  // conversions
  f2bf_vec<<<(NN * 128 / 4 + 255) / 256, 256, 0, stream>>>((const float4*)x, (uint2*)hx,
                                                           NN * 128 / 4);
  wtrans<<<(512 * 256 + 255) / 256, 256, 0, stream>>>(W1r, 128, W1o, 128, 512, wt1);
  wtrans<<<(512 * 1024 + 255) / 256, 256, 0, stream>>>(W2r, 512, W2o, 512, 512, wt2);
  wtrans<<<(512 * 1024 + 255) / 256, 256, 0, stream>>>(W3r, 512, W3o, 512, 512, wt3);
  wtrans<<<(64 * 512 + 255) / 256, 256, 0, stream>>>(Wl, 512, Wl, 0, 64, wtl);

  // layer 1
  agg_gather<2><<<(NN + 3) / 4, 256, 0, stream>>>(hx, 128, agg128, 128, rs, csr, NN);
  gemm_mfma<128><<<dim3(GRID_M, 4), 256, 0, stream>>>(agg128, 128, hx, 128, 128, 256, wt1,
                                                      b1, 1, h13, 512, (float*)nullptr, 0, NN);
  // layer 2
  agg_gather<8><<<(NN + 3) / 4, 256, 0, stream>>>(h13, 512, agg512, 512, rs, csr, NN);
  gemm_mfma<128><<<dim3(GRID_M, 4), 256, 0, stream>>>(agg512, 512, h13, 512, 512, 1024, wt2,
                                                      b2, 1, h2, 512, (float*)nullptr, 0, NN);
  // layer 3
  agg_gather<8><<<(NN + 3) / 4, 256, 0, stream>>>(h2, 512, agg512, 512, rs, csr, NN);
  gemm_mfma<128><<<dim3(GRID_M, 4), 256, 0, stream>>>(agg512, 512, h2, 512, 512, 1024, wt3,
                                                      b3, 1, h13, 512, out_embed, 512, NN);
  // head
  gemm_mfma<64><<<dim3(GRID_M, 1), 256, 0, stream>>>(h13, 512, h13, 512, 512, 512, wtl, bl,
                                                     0, (u16*)nullptr, 0, out_logits, 64, NN);
}